// Round 16
// baseline (1252.279 us; speedup 1.0000x reference)
//
#include <hip/hip_runtime.h>
#include <math.h>

#define B_ 4
#define T_ 2048
#define C_ 2048
#define H_ 16
#define HD_ 128

typedef __attribute__((ext_vector_type(8))) short short8;
typedef __attribute__((ext_vector_type(4))) float f32x4;
typedef unsigned short u16;
typedef unsigned int u32;

__device__ __forceinline__ u16 f2bf(float f) {
  union { float f; unsigned u; } v; v.f = f;
  unsigned r = v.u + 0x7FFFu + ((v.u >> 16) & 1u);
  return (u16)(r >> 16);
}

__device__ __forceinline__ u16 f2bf_trunc(float f) {
  union { float f; unsigned u; } v; v.f = f;
  return (u16)(v.u >> 16);
}

__device__ __forceinline__ void gld16(const void* g, void* l) {
  __builtin_amdgcn_global_load_lds(
      (__attribute__((address_space(1))) void*)(void*)g,
      (__attribute__((address_space(3))) void*)l, 16, 0, 0);
}

// ---------------- transpose fp32 (K x N) -> bf16 (N x K) ----------------
__global__ __launch_bounds__(256) void tconv(const float* __restrict__ in,
                                             u16* __restrict__ out,
                                             int K, int N,
                                             long inBS, long outBS) {
  __shared__ float tile[32][33];
  const float* inb = in + (long)blockIdx.z * inBS;
  u16* outb = out + (long)blockIdx.z * outBS;
  int k0 = blockIdx.x << 5, n0 = blockIdx.y << 5;
  int t = threadIdx.x;
  {
    int kk = t >> 3, nn = (t & 7) << 2;
    float4 v = *(const float4*)(inb + (long)(k0 + kk) * N + n0 + nn);
    tile[kk][nn + 0] = v.x; tile[kk][nn + 1] = v.y;
    tile[kk][nn + 2] = v.z; tile[kk][nn + 3] = v.w;
  }
  __syncthreads();
  {
    int nn = t >> 3, kk = (t & 7) << 2;
    ushort4 o;
    o.x = f2bf(tile[kk + 0][nn]); o.y = f2bf(tile[kk + 1][nn]);
    o.z = f2bf(tile[kk + 2][nn]); o.w = f2bf(tile[kk + 3][nn]);
    *(ushort4*)(outb + (long)(n0 + nn) * K + k0 + kk) = o;
  }
}

// ---------------- LayerNorm row kernel: fp32 in -> bf16 out ----------------
__global__ __launch_bounds__(256) void ln_rows(const float* __restrict__ x,
                                               const float* __restrict__ gam,
                                               const float* __restrict__ bet,
                                               u16* __restrict__ out) {
  int row = blockIdx.x;
  const float* xr = x + (size_t)row * C_;
  int t = threadIdx.x;
  float4 v0 = *(const float4*)(xr + t * 8);
  float4 v1 = *(const float4*)(xr + t * 8 + 4);
  float s = v0.x + v0.y + v0.z + v0.w + v1.x + v1.y + v1.z + v1.w;
  float ss = v0.x * v0.x + v0.y * v0.y + v0.z * v0.z + v0.w * v0.w +
             v1.x * v1.x + v1.y * v1.y + v1.z * v1.z + v1.w * v1.w;
  for (int d = 32; d > 0; d >>= 1) {
    s += __shfl_down(s, d);
    ss += __shfl_down(ss, d);
  }
  __shared__ float red[8];
  int wv = t >> 6;
  if ((t & 63) == 0) { red[wv] = s; red[4 + wv] = ss; }
  __syncthreads();
  s = red[0] + red[1] + red[2] + red[3];
  ss = red[4] + red[5] + red[6] + red[7];
  float mu = s * (1.0f / C_);
  float var = ss * (1.0f / C_) - mu * mu;
  float rs = rsqrtf(var + 1e-5f);
  int c = t * 8;
  float vv[8] = {v0.x, v0.y, v0.z, v0.w, v1.x, v1.y, v1.z, v1.w};
  ushort4 o0, o1;
  o0.x = f2bf((vv[0] - mu) * rs * gam[c + 0] + bet[c + 0]);
  o0.y = f2bf((vv[1] - mu) * rs * gam[c + 1] + bet[c + 1]);
  o0.z = f2bf((vv[2] - mu) * rs * gam[c + 2] + bet[c + 2]);
  o0.w = f2bf((vv[3] - mu) * rs * gam[c + 3] + bet[c + 3]);
  o1.x = f2bf((vv[4] - mu) * rs * gam[c + 4] + bet[c + 4]);
  o1.y = f2bf((vv[5] - mu) * rs * gam[c + 5] + bet[c + 5]);
  o1.z = f2bf((vv[6] - mu) * rs * gam[c + 6] + bet[c + 6]);
  o1.w = f2bf((vv[7] - mu) * rs * gam[c + 7] + bet[c + 7]);
  *(ushort4*)(out + (size_t)row * C_ + c) = o0;
  *(ushort4*)(out + (size_t)row * C_ + c + 4) = o1;
}

// ---------------- 256x256 bf16 GEMM, counted-vmcnt 2-phase K-loop -------------
// BM=BN=256, BK=64, 8 waves (2Mx4N), 128KB dynamic LDS. LDS slabs are K-MAJOR
// (slab = 256 rows x 32 k, 16KB) so phase-0 consumes the first-issued stage
// rounds and phase-1 the last: stage order per tile [Ak0,Ak0,Bk0,Bk0,Ak1,Ak1,
// Bk1,Bk1]. Steady state: issue 8 rounds for t+1 at top (outstanding 12) ->
// phase0 (k0, 32 MFMA) -> vmcnt(8)+s_barrier (publishes cur k1) -> phase1 ->
// vmcnt(4)+s_barrier (publishes t+1 k0; 4 in flight). Loads never drain to 0
// in the steady-state loop (T4). Swizzle slot^(row&3)^((row>>2)&3) both sides.
template <int EPI>
__global__ __launch_bounds__(512, 2) void gemm256(
    const u16* __restrict__ A, const u16* __restrict__ BT,
    int M, int N, int K, int lda, int ldb,
    u16* __restrict__ oq, u16* __restrict__ ok, u16* __restrict__ ovt,
    float* __restrict__ of32, const float* __restrict__ resid,
    const float* __restrict__ bias, u16* __restrict__ obf, int addBias) {
  extern __shared__ char smem[];  // A: 2buf x 2kslab x 16KB; B: same at +64K
  int nbx = N >> 8;
  int nwg = gridDim.x;
  int flat = blockIdx.x;
  int sw = (flat & 7) * (nwg >> 3) + (flat >> 3);  // nwg % 8 == 0 always
  int bx = sw % nbx, by = sw / nbx;
  int m0 = by << 8, n0 = bx << 8;
  int tid = threadIdx.x;
  int lane = tid & 63, wave = tid >> 6;
  int wm = wave >> 2, wn = wave & 3;
  int l15 = lane & 15, l16 = lane >> 4;
  int nt = K >> 6;

  f32x4 acc[8][4] = {};
  short8 af[8], bf[4];

  // round r of tile at k0 into buffer b: r0,1=A.k0  r2,3=B.k0  r4,5=A.k1  r6,7=B.k1
  auto stage = [&](int b, int r, int k0) {
    int isB = (r >> 1) & 1;
    int ks = r >> 2;
    int row = (r & 1) * 128 + (tid >> 2);
    int swz = (row & 3) ^ ((row >> 2) & 3);
    int gslot = (tid & 3) ^ swz;
    char* dst = smem + isB * 65536 + b * 32768 + ks * 16384 + (r & 1) * 8192 +
                tid * 16;
    const u16* src = (isB ? (BT + (long)(n0 + row) * ldb)
                          : (A + (long)(m0 + row) * lda)) +
                     k0 + ks * 32 + gslot * 8;
    gld16(src, dst);
  };
  auto ldA = [&](int b, int ks, int mf) {
    int row = wm * 128 + mf * 16 + l15;
    int swz = (row & 3) ^ ((row >> 2) & 3);
    return *(const short8*)(smem + b * 32768 + ks * 16384 + row * 64 +
                            ((l16 ^ swz) << 4));
  };
  auto ldB = [&](int b, int ks, int nf) {
    int row = wn * 64 + nf * 16 + l15;
    int swz = (row & 3) ^ ((row >> 2) & 3);
    return *(const short8*)(smem + 65536 + b * 32768 + ks * 16384 + row * 64 +
                            ((l16 ^ swz) << 4));
  };

  // prologue: stage tile 0; publish its k0 half (k1 stays in flight)
#pragma unroll
  for (int r = 0; r < 8; ++r) stage(0, r, 0);
  asm volatile("s_waitcnt vmcnt(4)" ::: "memory");
  __builtin_amdgcn_s_barrier();

  for (int t = 0; t < nt; ++t) {
    int cur = t & 1, nxt = cur ^ 1;
    bool more = (t + 1) < nt;
    int k1 = (t + 1) << 6;
    if (more) {
#pragma unroll
      for (int r = 0; r < 8; ++r) stage(nxt, r, k1);
    }
    // ---- phase 0: k-half 0 of cur ----
#pragma unroll
    for (int mf = 0; mf < 8; ++mf) af[mf] = ldA(cur, 0, mf);
#pragma unroll
    for (int nf = 0; nf < 4; ++nf) bf[nf] = ldB(cur, 0, nf);
    __builtin_amdgcn_s_setprio(1);
#pragma unroll
    for (int mf = 0; mf < 8; ++mf)
#pragma unroll
      for (int nf = 0; nf < 4; ++nf)
        acc[mf][nf] = __builtin_amdgcn_mfma_f32_16x16x32_bf16(
            af[mf], bf[nf], acc[mf][nf], 0, 0, 0);
    __builtin_amdgcn_s_setprio(0);
    if (more)
      asm volatile("s_waitcnt vmcnt(8)" ::: "memory");  // cur.k1 landed
    else
      asm volatile("s_waitcnt vmcnt(0)" ::: "memory");
    __builtin_amdgcn_s_barrier();
    // ---- phase 1: k-half 1 of cur ----
#pragma unroll
    for (int mf = 0; mf < 8; ++mf) af[mf] = ldA(cur, 1, mf);
#pragma unroll
    for (int nf = 0; nf < 4; ++nf) bf[nf] = ldB(cur, 1, nf);
    __builtin_amdgcn_s_setprio(1);
#pragma unroll
    for (int mf = 0; mf < 8; ++mf)
#pragma unroll
      for (int nf = 0; nf < 4; ++nf)
        acc[mf][nf] = __builtin_amdgcn_mfma_f32_16x16x32_bf16(
            af[mf], bf[nf], acc[mf][nf], 0, 0, 0);
    __builtin_amdgcn_s_setprio(0);
    if (more) {
      asm volatile("s_waitcnt vmcnt(4)" ::: "memory");  // t+1.k0 landed
      __builtin_amdgcn_s_barrier();  // also WAR: cur reads done before t+2
    }
  }

#pragma unroll
  for (int mf = 0; mf < 8; ++mf) {
#pragma unroll
    for (int nf = 0; nf < 4; ++nf) {
      int rowf = m0 + wm * 128 + mf * 16 + l16 * 4;
      int col = n0 + wn * 64 + nf * 16 + l15;
      if constexpr (EPI == 0) {
        int seg = col >> 11, cn = col & 2047;
        int hh = cn >> 7, dd = cn & 127;
        int bb = rowf >> 11, t0 = rowf & 2047;
        if (seg == 2) {
          ushort4 o;
          o.x = f2bf(acc[mf][nf][0]); o.y = f2bf(acc[mf][nf][1]);
          o.z = f2bf(acc[mf][nf][2]); o.w = f2bf(acc[mf][nf][3]);
          *(ushort4*)(ovt + ((long)(bb * H_ + hh) * HD_ + dd) * T_ + t0) = o;
        } else if (seg == 0) {
          const float qs = 0.08838834764831845f * 1.4426950408889634f;
#pragma unroll
          for (int r = 0; r < 4; ++r)
            oq[((long)(bb * H_ + hh) * T_ + t0 + r) * HD_ + dd] =
                f2bf(acc[mf][nf][r] * qs);
        } else {
#pragma unroll
          for (int r = 0; r < 4; ++r)
            ok[((long)(bb * H_ + hh) * T_ + t0 + r) * HD_ + dd] =
                f2bf(acc[mf][nf][r]);
        }
      } else if constexpr (EPI == 1) {
#pragma unroll
        for (int r = 0; r < 4; ++r) {
          long idx = (long)(rowf + r) * N + col;
          of32[idx] = resid[idx] + bias[col] + acc[mf][nf][r];
        }
      } else if constexpr (EPI == 2) {
#pragma unroll
        for (int r = 0; r < 4; ++r) {
          float v = acc[mf][nf][r] + bias[col];
          float g = 0.5f * v * (1.0f + erff(v * 0.70710678118654752f));
          obf[(long)(rowf + r) * N + col] = f2bf(g);
        }
      } else {
#pragma unroll
        for (int r = 0; r < 4; ++r) {
          long idx = (long)(rowf + r) * N + col;
          float v = acc[mf][nf][r];
          if (addBias) v += bias[col];
          of32[idx] += v;
        }
      }
    }
  }
}

// ---------------- flash attention (causal), bf16, D=128 (R15 best) -----------
__global__ __launch_bounds__(256) void attn_fwd(const u16* __restrict__ q,
                                                const u16* __restrict__ k,
                                                const u16* __restrict__ vt,
                                                u16* __restrict__ o) {
  extern __shared__ char asmem[];  // [Ks0 8K][Ks1 8K][Vs0 8K][Vs1 8K][Ps 4K]
  int bid = blockIdx.x;
  int bh = bid & 63;
  int qb = 31 - (bid >> 6);  // heavy-first, 0..31
  int q0 = qb << 6;
  int tid = threadIdx.x, lane = tid & 63, wave = tid >> 6;
  int l15 = lane & 15, l16 = lane >> 4;
  int wq0 = q0 + wave * 16;
  const u16* kbase = k + (long)bh * T_ * HD_;
  const u16* vbase = vt + (long)bh * HD_ * T_;
  char* Psw = asmem + 32768 + wave * 1024;  // [16][32] u16, 64B rows

  short8 qf[4];
#pragma unroll
  for (int kk = 0; kk < 4; ++kk)
    qf[kk] = *(const short8*)(q + ((long)bh * T_ + wq0 + l15) * HD_ +
                              kk * 32 + l16 * 8);

  short8 vone;
#pragma unroll
  for (int j = 0; j < 8; ++j) vone[j] = (short)0x3F80;  // bf16 1.0

  f32x4 accO[8] = {};
  float m_r[4], l_r[4];
#pragma unroll
  for (int r = 0; r < 4; ++r) { m_r[r] = -INFINITY; l_r[r] = 0.f; }

  int nt = 2 * qb + 2;  // KV tiles of 32

  auto stage = [&](int b, int t) {
    int s0 = t << 5;
    char* Kd = asmem + b * 8192;
    char* Vd = asmem + 16384 + b * 8192;
#pragma unroll
    for (int r = 0; r < 2; ++r) {
      int off = r * 4096 + tid * 16;
      int krow = off >> 8;                  // 256B rows, 16 slots
      int kslot = (tid & 15) ^ (krow & 7);
      gld16(kbase + (long)(s0 + krow) * HD_ + kslot * 8, Kd + off);
      int dd = off >> 6;                    // 64B rows, 4 slots
      int vslot = (tid & 3) ^ (dd & 3);
      gld16(vbase + (long)dd * T_ + s0 + vslot * 8, Vd + off);
    }
  };

  stage(0, 0);
  asm volatile("s_waitcnt vmcnt(0)" ::: "memory");
  __syncthreads();

  for (int t = 0; t < nt; ++t) {
    int s0 = t << 5;
    int cur = t & 1;
    bool more = (t + 1 < nt);
    if (more) stage(cur ^ 1, t + 1);  // flies during this tile's compute

    if (s0 <= wq0 + 15) {  // wave-uniform causal skip
      const char* Kc = asmem + cur * 8192;
      const char* Vc = asmem + 16384 + cur * 8192;
      bool needmask = (s0 + 31 > wq0);
      f32x4 S[2];
#pragma unroll
      for (int sb = 0; sb < 2; ++sb) {
        f32x4 s = {};
#pragma unroll
        for (int kk = 0; kk < 4; ++kk) {
          int srow = sb * 16 + l15;
          int kb = srow * 256 + (((kk * 4 + l16) ^ (srow & 7)) << 4);
          short8 kf = *(const short8*)(Kc + kb);
          s = __builtin_amdgcn_mfma_f32_16x16x32_bf16(qf[kk], kf, s, 0, 0, 0);
        }
        S[sb] = s;
      }
      float mxl[4];
      bool growL = false;
#pragma unroll
      for (int r = 0; r < 4; ++r) {
        int tt = wq0 + 4 * l16 + r;
        float mx = -INFINITY;
#pragma unroll
        for (int sb = 0; sb < 2; ++sb) {
          float v = S[sb][r];  // scale pre-folded into q
          if (needmask && (s0 + sb * 16 + l15 > tt)) v = -INFINITY;
          S[sb][r] = v;
          mx = fmaxf(mx, v);
        }
        mxl[r] = mx;
        growL = growL || (mx > m_r[r] + 8.0f);
      }
      bool anyg = __any(growL);
      float al[4];
      if (anyg) {
#pragma unroll
        for (int r = 0; r < 4; ++r) {
          float mx = mxl[r];
          mx = fmaxf(mx, __shfl_xor(mx, 1));
          mx = fmaxf(mx, __shfl_xor(mx, 2));
          mx = fmaxf(mx, __shfl_xor(mx, 4));
          mx = fmaxf(mx, __shfl_xor(mx, 8));
          float mo = m_r[r];
          float mn = fmaxf(mo, mx);
          al[r] = exp2f(mo - mn);
          m_r[r] = mn;
        }
      } else {
#pragma unroll
        for (int r = 0; r < 4; ++r) al[r] = 1.0f;
      }
#pragma unroll
      for (int r = 0; r < 4; ++r) {
        float mn = m_r[r];
        int prow = 4 * l16 + r;
#pragma unroll
        for (int sb = 0; sb < 2; ++sb) {
          float p = exp2f(S[sb][r] - mn);
          int col = sb * 16 + l15;
          int slot = col >> 3;
          int pb = prow * 64 + ((slot ^ l16) << 4) + (col & 7) * 2;
          *(u16*)(Psw + pb) = f2bf_trunc(p);
        }
      }
      if (anyg) {
#pragma unroll
        for (int db = 0; db < 8; ++db)
#pragma unroll
          for (int r = 0; r < 4; ++r) accO[db][r] *= al[r];
      }
      int pslot = l16 ^ ((l15 >> 2) & 3);
      short8 pf = *(const short8*)(Psw + l15 * 64 + (pslot << 4));
      f32x4 zz = {};
      f32x4 sacc = __builtin_amdgcn_mfma_f32_16x16x32_bf16(pf, vone, zz, 0, 0, 0);
#pragma unroll
      for (int r = 0; r < 4; ++r) l_r[r] = l_r[r] * al[r] + sacc[r];
#pragma unroll
      for (int db = 0; db < 8; ++db) {
        int vrow = db * 16 + l15;
        int vb = vrow * 64 + ((l16 ^ (vrow & 3)) << 4);
        short8 vf = *(const short8*)(Vc + vb);
        accO[db] = __builtin_amdgcn_mfma_f32_16x16x32_bf16(pf, vf,
                                                           accO[db], 0, 0, 0);
      }
    }
    if (more) asm volatile("s_waitcnt vmcnt(0)" ::: "memory");  // t+1 landed
    __syncthreads();  // all waves: done reading buf[cur], buf[cur^1] ready
  }

  int bb = bh >> 4, hh = bh & 15;
  float inv[4];
#pragma unroll
  for (int r = 0; r < 4; ++r) inv[r] = 1.0f / l_r[r];
#pragma unroll
  for (int db = 0; db < 8; ++db)
#pragma unroll
    for (int r = 0; r < 4; ++r) {
      int tt = wq0 + 4 * l16 + r;
      o[((long)bb * T_ + tt) * C_ + hh * HD_ + db * 16 + l15] =
          f2bf(accO[db][r] * inv[r]);
    }
}

extern "C" void kernel_launch(void* const* d_in, const int* in_sizes, int n_in,
                              void* d_out, int out_size, void* d_ws, size_t ws_size,
                              hipStream_t stream) {
  (void)in_sizes; (void)n_in; (void)out_size; (void)ws_size;
  const float* x   = (const float*)d_in[0];
  const float* Wq  = (const float*)d_in[1];
  const float* Wk  = (const float*)d_in[2];
  const float* Wv  = (const float*)d_in[3];
  const float* Wp  = (const float*)d_in[4];
  const float* bp  = (const float*)d_in[5];
  const float* W1  = (const float*)d_in[6];
  const float* b1  = (const float*)d_in[7];
  const float* W2  = (const float*)d_in[8];
  const float* b2  = (const float*)d_in[9];
  const float* g1  = (const float*)d_in[10];
  const float* be1 = (const float*)d_in[11];
  const float* g2  = (const float*)d_in[12];
  const float* be2 = (const float*)d_in[13];
  float* out = (float*)d_out;

  (void)hipFuncSetAttribute((const void*)gemm256<0>,
                            hipFuncAttributeMaxDynamicSharedMemorySize, 131072);
  (void)hipFuncSetAttribute((const void*)gemm256<1>,
                            hipFuncAttributeMaxDynamicSharedMemorySize, 131072);
  (void)hipFuncSetAttribute((const void*)gemm256<2>,
                            hipFuncAttributeMaxDynamicSharedMemorySize, 131072);
  (void)hipFuncSetAttribute((const void*)gemm256<3>,
                            hipFuncAttributeMaxDynamicSharedMemorySize, 131072);
  (void)hipFuncSetAttribute((const void*)attn_fwd,
                            hipFuncAttributeMaxDynamicSharedMemorySize, 36864);

  char* ws = (char*)d_ws;
  size_t off = 0;
  auto alloc = [&](size_t n) {
    void* p = ws + off;
    off += (n + 255) & ~(size_t)255;
    return p;
  };
  u16* wqkvT = (u16*)alloc((size_t)6144 * 2048 * 2);
  u16* wpT   = (u16*)alloc((size_t)2048 * 2048 * 2);
  u16* w1T   = (u16*)alloc((size_t)8192 * 2048 * 2);
  u16* w2T   = (u16*)alloc((size_t)2048 * 8192 * 2);
  u16* hb    = (u16*)alloc((size_t)8192 * 2048 * 2);
  u16* qbuf  = (u16*)alloc((size_t)8192 * 2048 * 2);
  u16* kbuf  = (u16*)alloc((size_t)8192 * 2048 * 2);
  u16* vtbuf = (u16*)alloc((size_t)8192 * 2048 * 2);
  u16* ob = hb;
  u16* fb = qbuf;  // FFN1 out spans qbuf+kbuf (64MB), dead after attention

  tconv<<<dim3(64, 4, 16), 256, 0, stream>>>(Wq, wqkvT, 2048, 128,
                                             (long)2048 * 128, (long)128 * 2048);
  tconv<<<dim3(64, 4, 16), 256, 0, stream>>>(Wk, wqkvT + (size_t)2048 * 2048, 2048, 128,
                                             (long)2048 * 128, (long)128 * 2048);
  tconv<<<dim3(64, 4, 16), 256, 0, stream>>>(Wv, wqkvT + (size_t)4096 * 2048, 2048, 128,
                                             (long)2048 * 128, (long)128 * 2048);
  tconv<<<dim3(64, 64, 1), 256, 0, stream>>>(Wp, wpT, 2048, 2048, 0, 0);
  tconv<<<dim3(64, 256, 1), 256, 0, stream>>>(W1, w1T, 2048, 8192, 0, 0);
  tconv<<<dim3(256, 64, 1), 256, 0, stream>>>(W2, w2T, 8192, 2048, 0, 0);

  ln_rows<<<8192, 256, 0, stream>>>(x, g1, be1, hb);
  gemm256<0><<<768, 512, 131072, stream>>>(hb, wqkvT, 8192, 6144, 2048, 2048, 2048,
                                           qbuf, kbuf, vtbuf, nullptr, nullptr,
                                           nullptr, nullptr, 0);
  attn_fwd<<<2048, 256, 36864, stream>>>(qbuf, kbuf, vtbuf, ob);
  gemm256<1><<<256, 512, 131072, stream>>>(ob, wpT, 8192, 2048, 2048, 2048, 2048,
                                           nullptr, nullptr, nullptr, out, x, bp,
                                           nullptr, 0);

  ln_rows<<<8192, 256, 0, stream>>>(out, g2, be2, hb);
  for (int c = 0; c < 2; ++c) {
    gemm256<2><<<512, 512, 131072, stream>>>(hb, w1T + (size_t)c * 4096 * 2048,
                                             8192, 4096, 2048, 2048, 2048,
                                             nullptr, nullptr, nullptr, nullptr,
                                             nullptr, b1 + c * 4096, fb, 0);
    gemm256<3><<<256, 512, 131072, stream>>>(fb, w2T + (size_t)c * 4096,
                                             8192, 2048, 4096, 4096, 8192,
                                             nullptr, nullptr, nullptr, out,
                                             nullptr, b2, nullptr, c == 0 ? 1 : 0);
  }
}

// Round 17
// 1080.931 us; speedup vs baseline: 1.1585x; 1.1585x over previous
//
#include <hip/hip_runtime.h>
#include <math.h>

#define B_ 4
#define T_ 2048
#define C_ 2048
#define H_ 16
#define HD_ 128

typedef __attribute__((ext_vector_type(8))) short short8;
typedef __attribute__((ext_vector_type(4))) float f32x4;
typedef unsigned short u16;
typedef unsigned int u32;

__device__ __forceinline__ u16 f2bf(float f) {
  union { float f; unsigned u; } v; v.f = f;
  unsigned r = v.u + 0x7FFFu + ((v.u >> 16) & 1u);
  return (u16)(r >> 16);
}

__device__ __forceinline__ u16 f2bf_trunc(float f) {
  union { float f; unsigned u; } v; v.f = f;
  return (u16)(v.u >> 16);
}

__device__ __forceinline__ void gld16(const void* g, void* l) {
  __builtin_amdgcn_global_load_lds(
      (__attribute__((address_space(1))) void*)(void*)g,
      (__attribute__((address_space(3))) void*)l, 16, 0, 0);
}

// ---------------- transpose fp32 (K x N) -> bf16 (N x K) ----------------
__global__ __launch_bounds__(256) void tconv(const float* __restrict__ in,
                                             u16* __restrict__ out,
                                             int K, int N,
                                             long inBS, long outBS) {
  __shared__ float tile[32][33];
  const float* inb = in + (long)blockIdx.z * inBS;
  u16* outb = out + (long)blockIdx.z * outBS;
  int k0 = blockIdx.x << 5, n0 = blockIdx.y << 5;
  int t = threadIdx.x;
  {
    int kk = t >> 3, nn = (t & 7) << 2;
    float4 v = *(const float4*)(inb + (long)(k0 + kk) * N + n0 + nn);
    tile[kk][nn + 0] = v.x; tile[kk][nn + 1] = v.y;
    tile[kk][nn + 2] = v.z; tile[kk][nn + 3] = v.w;
  }
  __syncthreads();
  {
    int nn = t >> 3, kk = (t & 7) << 2;
    ushort4 o;
    o.x = f2bf(tile[kk + 0][nn]); o.y = f2bf(tile[kk + 1][nn]);
    o.z = f2bf(tile[kk + 2][nn]); o.w = f2bf(tile[kk + 3][nn]);
    *(ushort4*)(outb + (long)(n0 + nn) * K + k0 + kk) = o;
  }
}

// ---------------- LayerNorm row kernel: fp32 in -> bf16 out ----------------
__global__ __launch_bounds__(256) void ln_rows(const float* __restrict__ x,
                                               const float* __restrict__ gam,
                                               const float* __restrict__ bet,
                                               u16* __restrict__ out) {
  int row = blockIdx.x;
  const float* xr = x + (size_t)row * C_;
  int t = threadIdx.x;
  float4 v0 = *(const float4*)(xr + t * 8);
  float4 v1 = *(const float4*)(xr + t * 8 + 4);
  float s = v0.x + v0.y + v0.z + v0.w + v1.x + v1.y + v1.z + v1.w;
  float ss = v0.x * v0.x + v0.y * v0.y + v0.z * v0.z + v0.w * v0.w +
             v1.x * v1.x + v1.y * v1.y + v1.z * v1.z + v1.w * v1.w;
  for (int d = 32; d > 0; d >>= 1) {
    s += __shfl_down(s, d);
    ss += __shfl_down(ss, d);
  }
  __shared__ float red[8];
  int wv = t >> 6;
  if ((t & 63) == 0) { red[wv] = s; red[4 + wv] = ss; }
  __syncthreads();
  s = red[0] + red[1] + red[2] + red[3];
  ss = red[4] + red[5] + red[6] + red[7];
  float mu = s * (1.0f / C_);
  float var = ss * (1.0f / C_) - mu * mu;
  float rs = rsqrtf(var + 1e-5f);
  int c = t * 8;
  float vv[8] = {v0.x, v0.y, v0.z, v0.w, v1.x, v1.y, v1.z, v1.w};
  ushort4 o0, o1;
  o0.x = f2bf((vv[0] - mu) * rs * gam[c + 0] + bet[c + 0]);
  o0.y = f2bf((vv[1] - mu) * rs * gam[c + 1] + bet[c + 1]);
  o0.z = f2bf((vv[2] - mu) * rs * gam[c + 2] + bet[c + 2]);
  o0.w = f2bf((vv[3] - mu) * rs * gam[c + 3] + bet[c + 3]);
  o1.x = f2bf((vv[4] - mu) * rs * gam[c + 4] + bet[c + 4]);
  o1.y = f2bf((vv[5] - mu) * rs * gam[c + 5] + bet[c + 5]);
  o1.z = f2bf((vv[6] - mu) * rs * gam[c + 6] + bet[c + 6]);
  o1.w = f2bf((vv[7] - mu) * rs * gam[c + 7] + bet[c + 7]);
  *(ushort4*)(out + (size_t)row * C_ + c) = o0;
  *(ushort4*)(out + (size_t)row * C_ + c + 4) = o1;
}

// ---------------- 256x256 bf16 GEMM, single-barrier pipelined K-loop ----------
// R15 structure (measured best: QKV 195us, 0 bank conflicts, MfmaUtil 48%).
// launch_bounds (512,1): LDS (128KB) caps residency at 1 block/CU anyway, so
// the old min=2 declaration only clamped the allocator to 128 VGPR (R15's
// counter showed exactly 128 = at-cap pressure). min=1 frees the budget for
// deeper preload scheduling at zero occupancy cost.
template <int EPI>
__global__ __launch_bounds__(512, 1) void gemm256(
    const u16* __restrict__ A, const u16* __restrict__ BT,
    int M, int N, int K, int lda, int ldb,
    u16* __restrict__ oq, u16* __restrict__ ok, u16* __restrict__ ovt,
    float* __restrict__ of32, const float* __restrict__ resid,
    const float* __restrict__ bias, u16* __restrict__ obf, int addBias) {
  extern __shared__ char smem[];  // [A: 2x32768][B: 2x32768]
  int nbx = N >> 8;
  int nwg = gridDim.x;
  int flat = blockIdx.x;
  int sw = (flat & 7) * (nwg >> 3) + (flat >> 3);  // nwg % 8 == 0 always
  int bx = sw % nbx, by = sw / nbx;
  int m0 = by << 8, n0 = bx << 8;
  int tid = threadIdx.x;
  int lane = tid & 63, wave = tid >> 6;
  int wm = wave >> 2, wn = wave & 3;
  int l15 = lane & 15, l16 = lane >> 4;
  int nt = K >> 6;

  f32x4 acc[8][4] = {};
  short8 afA[4][2], afB[4][2], bfA[2][2], bfB[2][2];

  auto stage = [&](int b, int r, int k0) {
    int row = (r & 3) * 64 + (tid >> 3);
    int lslot = (tid & 7) ^ (row & 7);
    char* dst = smem + ((r < 4) ? 0 : 65536) + b * 32768 + (r & 3) * 8192 + tid * 16;
    const u16* src = ((r < 4) ? (A + (long)(m0 + row) * lda)
                              : (BT + (long)(n0 + row) * ldb)) +
                     k0 + lslot * 8;
    gld16(src, dst);
  };
  auto ldA = [&](int cur, int mf, int kk) {
    int row = wm * 128 + mf * 16 + l15;
    int slot = (kk * 4 + l16) ^ (row & 7);
    return *(const short8*)(smem + cur * 32768 + row * 128 + slot * 16);
  };
  auto ldB = [&](int cur, int nf, int kk) {
    int row = wn * 64 + nf * 16 + l15;
    int slot = (kk * 4 + l16) ^ (row & 7);
    return *(const short8*)(smem + 65536 + cur * 32768 + row * 128 + slot * 16);
  };

#pragma unroll
  for (int r = 0; r < 8; ++r) stage(0, r, 0);
  __syncthreads();  // implicit vmcnt(0): tile 0 landed for all waves

  // preload phase-0 fragments of tile 0
#pragma unroll
  for (int mq = 0; mq < 4; ++mq)
#pragma unroll
    for (int kk = 0; kk < 2; ++kk) afA[mq][kk] = ldA(0, mq, kk);
#pragma unroll
  for (int nq = 0; nq < 2; ++nq)
#pragma unroll
    for (int kk = 0; kk < 2; ++kk) bfA[nq][kk] = ldB(0, nq, kk);

  for (int t = 0; t < nt; ++t) {
    int cur = t & 1, nxt = cur ^ 1;
    bool more = (t + 1) < nt;
    int k1 = (t + 1) << 6;
    if (more) {
#pragma unroll
      for (int r = 0; r < 8; ++r) stage(nxt, r, k1);  // fly during compute
    }
    // P0 (m0 x n01) — preload bfB for P1 first, reads hide under MFMA
#pragma unroll
    for (int nq = 0; nq < 2; ++nq)
#pragma unroll
      for (int kk = 0; kk < 2; ++kk) bfB[nq][kk] = ldB(cur, 2 + nq, kk);
    __builtin_amdgcn_s_setprio(1);
#pragma unroll
    for (int mq = 0; mq < 4; ++mq)
#pragma unroll
      for (int nq = 0; nq < 2; ++nq)
#pragma unroll
        for (int kk = 0; kk < 2; ++kk)
          acc[mq][nq] = __builtin_amdgcn_mfma_f32_16x16x32_bf16(
              afA[mq][kk], bfA[nq][kk], acc[mq][nq], 0, 0, 0);
    __builtin_amdgcn_s_setprio(0);
    // P1 (m0 x n23) — preload afB for P2
#pragma unroll
    for (int mq = 0; mq < 4; ++mq)
#pragma unroll
      for (int kk = 0; kk < 2; ++kk) afB[mq][kk] = ldA(cur, 4 + mq, kk);
    __builtin_amdgcn_s_setprio(1);
#pragma unroll
    for (int mq = 0; mq < 4; ++mq)
#pragma unroll
      for (int nq = 0; nq < 2; ++nq)
#pragma unroll
        for (int kk = 0; kk < 2; ++kk)
          acc[mq][2 + nq] = __builtin_amdgcn_mfma_f32_16x16x32_bf16(
              afA[mq][kk], bfB[nq][kk], acc[mq][2 + nq], 0, 0, 0);
    __builtin_amdgcn_s_setprio(0);
    // P2 (m1 x n01)
    __builtin_amdgcn_s_setprio(1);
#pragma unroll
    for (int mq = 0; mq < 4; ++mq)
#pragma unroll
      for (int nq = 0; nq < 2; ++nq)
#pragma unroll
        for (int kk = 0; kk < 2; ++kk)
          acc[4 + mq][nq] = __builtin_amdgcn_mfma_f32_16x16x32_bf16(
              afB[mq][kk], bfA[nq][kk], acc[4 + mq][nq], 0, 0, 0);
    __builtin_amdgcn_s_setprio(0);
    // P3 (m1 x n23)
    __builtin_amdgcn_s_setprio(1);
#pragma unroll
    for (int mq = 0; mq < 4; ++mq)
#pragma unroll
      for (int nq = 0; nq < 2; ++nq)
#pragma unroll
        for (int kk = 0; kk < 2; ++kk)
          acc[4 + mq][2 + nq] = __builtin_amdgcn_mfma_f32_16x16x32_bf16(
              afB[mq][kk], bfB[nq][kk], acc[4 + mq][2 + nq], 0, 0, 0);
    __builtin_amdgcn_s_setprio(0);
    if (more) {
      __syncthreads();  // drains vmcnt: t+1 landed; all reads of cur complete
      // preload phase-0 fragments of t+1 (reads nxt — safe post-barrier)
#pragma unroll
      for (int mq = 0; mq < 4; ++mq)
#pragma unroll
        for (int kk = 0; kk < 2; ++kk) afA[mq][kk] = ldA(nxt, mq, kk);
#pragma unroll
      for (int nq = 0; nq < 2; ++nq)
#pragma unroll
        for (int kk = 0; kk < 2; ++kk) bfA[nq][kk] = ldB(nxt, nq, kk);
    }
  }

#pragma unroll
  for (int mf = 0; mf < 8; ++mf) {
#pragma unroll
    for (int nf = 0; nf < 4; ++nf) {
      int rowf = m0 + wm * 128 + mf * 16 + l16 * 4;
      int col = n0 + wn * 64 + nf * 16 + l15;
      if constexpr (EPI == 0) {
        int seg = col >> 11, cn = col & 2047;
        int hh = cn >> 7, dd = cn & 127;
        int bb = rowf >> 11, t0 = rowf & 2047;
        if (seg == 2) {
          ushort4 o;
          o.x = f2bf(acc[mf][nf][0]); o.y = f2bf(acc[mf][nf][1]);
          o.z = f2bf(acc[mf][nf][2]); o.w = f2bf(acc[mf][nf][3]);
          *(ushort4*)(ovt + ((long)(bb * H_ + hh) * HD_ + dd) * T_ + t0) = o;
        } else if (seg == 0) {
          const float qs = 0.08838834764831845f * 1.4426950408889634f;
#pragma unroll
          for (int r = 0; r < 4; ++r)
            oq[((long)(bb * H_ + hh) * T_ + t0 + r) * HD_ + dd] =
                f2bf(acc[mf][nf][r] * qs);
        } else {
#pragma unroll
          for (int r = 0; r < 4; ++r)
            ok[((long)(bb * H_ + hh) * T_ + t0 + r) * HD_ + dd] =
                f2bf(acc[mf][nf][r]);
        }
      } else if constexpr (EPI == 1) {
#pragma unroll
        for (int r = 0; r < 4; ++r) {
          long idx = (long)(rowf + r) * N + col;
          of32[idx] = resid[idx] + bias[col] + acc[mf][nf][r];
        }
      } else if constexpr (EPI == 2) {
#pragma unroll
        for (int r = 0; r < 4; ++r) {
          float v = acc[mf][nf][r] + bias[col];
          float g = 0.5f * v * (1.0f + erff(v * 0.70710678118654752f));
          obf[(long)(rowf + r) * N + col] = f2bf(g);
        }
      } else {
#pragma unroll
        for (int r = 0; r < 4; ++r) {
          long idx = (long)(rowf + r) * N + col;
          float v = acc[mf][nf][r];
          if (addBias) v += bias[col];
          of32[idx] += v;
        }
      }
    }
  }
}

// ---------------- flash attention (causal), bf16, D=128 (R15 best) -----------
// KVBLK=32, 36KB LDS, 4 blocks/CU. dbuf global_load_lds staging, XOR-swizzled
// K/V/Ps. Scale pre-folded into q. Row-sum l via one MFMA with ones-B
// (sacc[r] = row sum in all lanes). Lazy max-reduce + defer-max THR=8.
__global__ __launch_bounds__(256) void attn_fwd(const u16* __restrict__ q,
                                                const u16* __restrict__ k,
                                                const u16* __restrict__ vt,
                                                u16* __restrict__ o) {
  extern __shared__ char asmem[];  // [Ks0 8K][Ks1 8K][Vs0 8K][Vs1 8K][Ps 4K]
  int bid = blockIdx.x;
  int bh = bid & 63;
  int qb = 31 - (bid >> 6);  // heavy-first, 0..31
  int q0 = qb << 6;
  int tid = threadIdx.x, lane = tid & 63, wave = tid >> 6;
  int l15 = lane & 15, l16 = lane >> 4;
  int wq0 = q0 + wave * 16;
  const u16* kbase = k + (long)bh * T_ * HD_;
  const u16* vbase = vt + (long)bh * HD_ * T_;
  char* Psw = asmem + 32768 + wave * 1024;  // [16][32] u16, 64B rows

  short8 qf[4];
#pragma unroll
  for (int kk = 0; kk < 4; ++kk)
    qf[kk] = *(const short8*)(q + ((long)bh * T_ + wq0 + l15) * HD_ +
                              kk * 32 + l16 * 8);

  short8 vone;
#pragma unroll
  for (int j = 0; j < 8; ++j) vone[j] = (short)0x3F80;  // bf16 1.0

  f32x4 accO[8] = {};
  float m_r[4], l_r[4];
#pragma unroll
  for (int r = 0; r < 4; ++r) { m_r[r] = -INFINITY; l_r[r] = 0.f; }

  int nt = 2 * qb + 2;  // KV tiles of 32

  auto stage = [&](int b, int t) {
    int s0 = t << 5;
    char* Kd = asmem + b * 8192;
    char* Vd = asmem + 16384 + b * 8192;
#pragma unroll
    for (int r = 0; r < 2; ++r) {
      int off = r * 4096 + tid * 16;
      int krow = off >> 8;                  // 256B rows, 16 slots
      int kslot = (tid & 15) ^ (krow & 7);
      gld16(kbase + (long)(s0 + krow) * HD_ + kslot * 8, Kd + off);
      int dd = off >> 6;                    // 64B rows, 4 slots
      int vslot = (tid & 3) ^ (dd & 3);
      gld16(vbase + (long)dd * T_ + s0 + vslot * 8, Vd + off);
    }
  };

  stage(0, 0);
  asm volatile("s_waitcnt vmcnt(0)" ::: "memory");
  __syncthreads();

  for (int t = 0; t < nt; ++t) {
    int s0 = t << 5;
    int cur = t & 1;
    bool more = (t + 1 < nt);
    if (more) stage(cur ^ 1, t + 1);  // flies during this tile's compute

    if (s0 <= wq0 + 15) {  // wave-uniform causal skip
      const char* Kc = asmem + cur * 8192;
      const char* Vc = asmem + 16384 + cur * 8192;
      bool needmask = (s0 + 31 > wq0);
      f32x4 S[2];
#pragma unroll
      for (int sb = 0; sb < 2; ++sb) {
        f32x4 s = {};
#pragma unroll
        for (int kk = 0; kk < 4; ++kk) {
          int srow = sb * 16 + l15;
          int kb = srow * 256 + (((kk * 4 + l16) ^ (srow & 7)) << 4);
          short8 kf = *(const short8*)(Kc + kb);
          s = __builtin_amdgcn_mfma_f32_16x16x32_bf16(qf[kk], kf, s, 0, 0, 0);
        }
        S[sb] = s;
      }
      float mxl[4];
      bool growL = false;
#pragma unroll
      for (int r = 0; r < 4; ++r) {
        int tt = wq0 + 4 * l16 + r;
        float mx = -INFINITY;
#pragma unroll
        for (int sb = 0; sb < 2; ++sb) {
          float v = S[sb][r];  // scale pre-folded into q
          if (needmask && (s0 + sb * 16 + l15 > tt)) v = -INFINITY;
          S[sb][r] = v;
          mx = fmaxf(mx, v);
        }
        mxl[r] = mx;
        growL = growL || (mx > m_r[r] + 8.0f);
      }
      bool anyg = __any(growL);
      float al[4];
      if (anyg) {
#pragma unroll
        for (int r = 0; r < 4; ++r) {
          float mx = mxl[r];
          mx = fmaxf(mx, __shfl_xor(mx, 1));
          mx = fmaxf(mx, __shfl_xor(mx, 2));
          mx = fmaxf(mx, __shfl_xor(mx, 4));
          mx = fmaxf(mx, __shfl_xor(mx, 8));
          float mo = m_r[r];
          float mn = fmaxf(mo, mx);
          al[r] = exp2f(mo - mn);
          m_r[r] = mn;
        }
      } else {
#pragma unroll
        for (int r = 0; r < 4; ++r) al[r] = 1.0f;
      }
#pragma unroll
      for (int r = 0; r < 4; ++r) {
        float mn = m_r[r];
        int prow = 4 * l16 + r;
#pragma unroll
        for (int sb = 0; sb < 2; ++sb) {
          float p = exp2f(S[sb][r] - mn);
          int col = sb * 16 + l15;
          int slot = col >> 3;
          int pb = prow * 64 + ((slot ^ l16) << 4) + (col & 7) * 2;
          *(u16*)(Psw + pb) = f2bf_trunc(p);
        }
      }
      if (anyg) {
#pragma unroll
        for (int db = 0; db < 8; ++db)
#pragma unroll
          for (int r = 0; r < 4; ++r) accO[db][r] *= al[r];
      }
      int pslot = l16 ^ ((l15 >> 2) & 3);
      short8 pf = *(const short8*)(Psw + l15 * 64 + (pslot << 4));
      f32x4 zz = {};
      f32x4 sacc = __builtin_amdgcn_mfma_f32_16x16x32_bf16(pf, vone, zz, 0, 0, 0);
#pragma unroll
      for (int r = 0; r < 4; ++r) l_r[r] = l_r[r] * al[r] + sacc[r];
#pragma unroll
      for (int db = 0; db < 8; ++db) {
        int vrow = db * 16 + l15;
        int vb = vrow * 64 + ((l16 ^ (vrow & 3)) << 4);
        short8 vf = *(const short8*)(Vc + vb);
        accO[db] = __builtin_amdgcn_mfma_f32_16x16x32_bf16(pf, vf,
                                                           accO[db], 0, 0, 0);
      }
    }
    if (more) asm volatile("s_waitcnt vmcnt(0)" ::: "memory");  // t+1 landed
    __syncthreads();  // all waves: done reading buf[cur], buf[cur^1] ready
  }

  int bb = bh >> 4, hh = bh & 15;
  float inv[4];
#pragma unroll
  for (int r = 0; r < 4; ++r) inv[r] = 1.0f / l_r[r];
#pragma unroll
  for (int db = 0; db < 8; ++db)
#pragma unroll
    for (int r = 0; r < 4; ++r) {
      int tt = wq0 + 4 * l16 + r;
      o[((long)bb * T_ + tt) * C_ + hh * HD_ + db * 16 + l15] =
          f2bf(accO[db][r] * inv[r]);
    }
}

extern "C" void kernel_launch(void* const* d_in, const int* in_sizes, int n_in,
                              void* d_out, int out_size, void* d_ws, size_t ws_size,
                              hipStream_t stream) {
  (void)in_sizes; (void)n_in; (void)out_size; (void)ws_size;
  const float* x   = (const float*)d_in[0];
  const float* Wq  = (const float*)d_in[1];
  const float* Wk  = (const float*)d_in[2];
  const float* Wv  = (const float*)d_in[3];
  const float* Wp  = (const float*)d_in[4];
  const float* bp  = (const float*)d_in[5];
  const float* W1  = (const float*)d_in[6];
  const float* b1  = (const float*)d_in[7];
  const float* W2  = (const float*)d_in[8];
  const float* b2  = (const float*)d_in[9];
  const float* g1  = (const float*)d_in[10];
  const float* be1 = (const float*)d_in[11];
  const float* g2  = (const float*)d_in[12];
  const float* be2 = (const float*)d_in[13];
  float* out = (float*)d_out;

  (void)hipFuncSetAttribute((const void*)gemm256<0>,
                            hipFuncAttributeMaxDynamicSharedMemorySize, 131072);
  (void)hipFuncSetAttribute((const void*)gemm256<1>,
                            hipFuncAttributeMaxDynamicSharedMemorySize, 131072);
  (void)hipFuncSetAttribute((const void*)gemm256<2>,
                            hipFuncAttributeMaxDynamicSharedMemorySize, 131072);
  (void)hipFuncSetAttribute((const void*)gemm256<3>,
                            hipFuncAttributeMaxDynamicSharedMemorySize, 131072);
  (void)hipFuncSetAttribute((const void*)attn_fwd,
                            hipFuncAttributeMaxDynamicSharedMemorySize, 36864);

  char* ws = (char*)d_ws;
  size_t off = 0;
  auto alloc = [&](size_t n) {
    void* p = ws + off;
    off += (n + 255) & ~(size_t)255;
    return p;
  };
  u16* wqkvT = (u16*)alloc((size_t)6144 * 2048 * 2);
  u16* wpT   = (u16*)alloc((size_t)2048 * 2048 * 2);
  u16* w1T   = (u16*)alloc((size_t)8192 * 2048 * 2);
  u16* w2T   = (u16*)alloc((size_t)2048 * 8192 * 2);
  u16* hb    = (u16*)alloc((size_t)8192 * 2048 * 2);
  u16* qbuf  = (u16*)alloc((size_t)8192 * 2048 * 2);
  u16* kbuf  = (u16*)alloc((size_t)8192 * 2048 * 2);
  u16* vtbuf = (u16*)alloc((size_t)8192 * 2048 * 2);
  u16* ob = hb;
  u16* fb = qbuf;  // FFN1 out spans qbuf+kbuf (64MB), dead after attention

  tconv<<<dim3(64, 4, 16), 256, 0, stream>>>(Wq, wqkvT, 2048, 128,
                                             (long)2048 * 128, (long)128 * 2048);
  tconv<<<dim3(64, 4, 16), 256, 0, stream>>>(Wk, wqkvT + (size_t)2048 * 2048, 2048, 128,
                                             (long)2048 * 128, (long)128 * 2048);
  tconv<<<dim3(64, 4, 16), 256, 0, stream>>>(Wv, wqkvT + (size_t)4096 * 2048, 2048, 128,
                                             (long)2048 * 128, (long)128 * 2048);
  tconv<<<dim3(64, 64, 1), 256, 0, stream>>>(Wp, wpT, 2048, 2048, 0, 0);
  tconv<<<dim3(64, 256, 1), 256, 0, stream>>>(W1, w1T, 2048, 8192, 0, 0);
  tconv<<<dim3(256, 64, 1), 256, 0, stream>>>(W2, w2T, 8192, 2048, 0, 0);

  ln_rows<<<8192, 256, 0, stream>>>(x, g1, be1, hb);
  gemm256<0><<<768, 512, 131072, stream>>>(hb, wqkvT, 8192, 6144, 2048, 2048, 2048,
                                           qbuf, kbuf, vtbuf, nullptr, nullptr,
                                           nullptr, nullptr, 0);
  attn_fwd<<<2048, 256, 36864, stream>>>(qbuf, kbuf, vtbuf, ob);
  gemm256<1><<<256, 512, 131072, stream>>>(ob, wpT, 8192, 2048, 2048, 2048, 2048,
                                           nullptr, nullptr, nullptr, out, x, bp,
                                           nullptr, 0);

  ln_rows<<<8192, 256, 0, stream>>>(out, g2, be2, hb);
  for (int c = 0; c < 2; ++c) {
    gemm256<2><<<512, 512, 131072, stream>>>(hb, w1T + (size_t)c * 4096 * 2048,
                                             8192, 4096, 2048, 2048, 2048,
                                             nullptr, nullptr, nullptr, nullptr,
                                             nullptr, b1 + c * 4096, fb, 0);
    gemm256<3><<<256, 512, 131072, stream>>>(fb, w2T + (size_t)c * 4096,
                                             8192, 2048, 4096, 4096, 8192,
                                             nullptr, nullptr, nullptr, out,
                                             nullptr, b2, nullptr, c == 0 ? 1 : 0);
  }
}